// Round 1
// 75.041 us; speedup vs baseline: 1.0072x; 1.0072x over previous
//
#include <hip/hip_runtime.h>

typedef _Float16 f16x8 __attribute__((ext_vector_type(8)));
typedef _Float16 f16x4 __attribute__((ext_vector_type(4)));
typedef float    f32x4 __attribute__((ext_vector_type(4)));

#define FDIM 64
#define EDIM 32
#define ADIM 4
#define XH_S 40   // halves; rows 80B -> bank starts 20*i mod 32, 2-way max = free

// One batch per 256-thread block; the 10 upper-tri 16x16 tiles are dealt
// round-robin to the 4 waves (t = wave + 4*tt): 3/3/2/2 tiles per wave.
// Each wave produces local softmax stats {M, psum, dot}; exact merge in LDS.

__global__ __launch_bounds__(256, 4)
void afm_kernel(const float* __restrict__ x,
                const float* __restrict__ attn_w,
                const float* __restrict__ attn_b,
                const float* __restrict__ attn_h,
                const float* __restrict__ pool_w,
                const float* __restrict__ pool_b,
                float* __restrict__ out)
{
    __shared__ _Float16 Xh[FDIM * XH_S];   // x slab fp16 [i][e], one batch
    __shared__ _Float16 Wh[ADIM * EDIM];   // w[a][e] fp16
    __shared__ _Float16 Pwh[EDIM];         // pool_w fp16
    __shared__ float    red[4][3];         // per-wave {M, psum, dot}

    const int tid  = threadIdx.x;
    const int wave = tid >> 6;
    const int lane = tid & 63;
    const int n16  = lane & 15;   // MFMA m/n index within 16-tile
    const int q    = lane >> 4;   // quad -> k-chunk / C-row group

    const int batch = blockIdx.x;
    const float* xb = x + (size_t)batch * (FDIM * EDIM);

    // ---- stage x -> fp16 LDS [i][e], coalesced float4, 2 per thread ----
    #pragma unroll
    for (int k = 0; k < 2; ++k) {
        int idx = tid + 256 * k;          // 512 float4 = 64x32 floats
        float4 v = ((const float4*)xb)[idx];
        int row = idx >> 3, c4 = idx & 7;
        f16x4 hv = {(_Float16)v.x, (_Float16)v.y, (_Float16)v.z, (_Float16)v.w};
        *(f16x4*)&Xh[row * XH_S + c4 * 4] = hv;
    }
    if (tid < ADIM * EDIM) {              // stage attn_w transposed -> [a][e]
        int a = tid >> 5, e = tid & 31;
        Wh[a * EDIM + e] = (_Float16)attn_w[e * ADIM + a];
    } else if (tid < ADIM * EDIM + EDIM) {
        int e = tid - ADIM * EDIM;
        Pwh[e] = (_Float16)pool_w[e];
    }
    float hb[ADIM], hh[ADIM];
    #pragma unroll
    for (int a = 0; a < ADIM; ++a) { hb[a] = attn_b[a]; hh[a] = attn_h[a]; }
    __syncthreads();

    // ---- this wave's tiles: t = wave + 4*tt; (mt,nt) packed in hex tables ----
    const int NT = (wave < 2) ? 3 : 2;
    int mt_[3], nt_[3], diag_[3];
    #pragma unroll
    for (int tt = 0; tt < 3; ++tt) {
        int t = wave + 4 * tt;            // t in [0,12); entries >=10 unused
        mt_[tt]  = (int)((0x3221110000ULL >> (4 * t)) & 0xF);
        nt_[tt]  = (int)((0x3323213210ULL >> (4 * t)) & 0xF);
        diag_[tt] = (mt_[tt] == nt_[tt]);
    }

    // ---- fragments (compile-time-indexed registers only; no scratch) ----
    f16x8 wfrag[ADIM];
    #pragma unroll
    for (int a = 0; a < ADIM; ++a)
        wfrag[a] = *(const f16x8*)&Wh[a * EDIM + q * 8];
    f16x8 pwf = *(const f16x8*)&Pwh[q * 8];

    f16x8 fa[3], fb[3];
    float val[3][4];
    #pragma unroll
    for (int tt = 0; tt < 3; ++tt) {
        #pragma unroll
        for (int r = 0; r < 4; ++r) val[tt][r] = 0.f;
        if (tt < NT) {
            fa[tt] = *(const f16x8*)&Xh[(mt_[tt] * 16 + n16) * XH_S + q * 8];
            fb[tt] = *(const f16x8*)&Xh[(nt_[tt] * 16 + n16) * XH_S + q * 8];
        }
    }

    // ---- scores: s[i,j] = sum_a h_a * relu( (x_i*w_a) . x_j + b_a ) ----
    #pragma unroll
    for (int tt = 0; tt < 3; ++tt) {
        if (tt < NT) {
            #pragma unroll
            for (int a = 0; a < ADIM; ++a) {
                f16x8 ya = fa[tt] * wfrag[a];      // v_pk_mul_f16
                f32x4 z = {0.f, 0.f, 0.f, 0.f};
                f32x4 acc = __builtin_amdgcn_mfma_f32_16x16x32_f16(ya, fb[tt], z, 0, 0, 0);
                #pragma unroll
                for (int r = 0; r < 4; ++r)
                    val[tt][r] += fmaxf(acc[r] + hb[a], 0.f) * hh[a];
            }
        }
    }

    // ---- wave-local masked softmax stats ----
    // C layout: row i = mt*16 + q*4 + r, col j = nt*16 + n16; valid iff i<j
    float M = -3e38f;
    #pragma unroll
    for (int tt = 0; tt < 3; ++tt) {
        if (tt < NT) {
            #pragma unroll
            for (int r = 0; r < 4; ++r) {
                bool valid = !diag_[tt] || ((q * 4 + r) < n16);
                if (valid) M = fmaxf(M, val[tt][r]);
            }
        }
    }
    #pragma unroll
    for (int off = 32; off >= 1; off >>= 1)
        M = fmaxf(M, __shfl_xor(M, off));

    float psum = 0.f;
    #pragma unroll
    for (int tt = 0; tt < 3; ++tt) {
        if (tt < NT) {
            #pragma unroll
            for (int r = 0; r < 4; ++r) {
                bool valid = !diag_[tt] || ((q * 4 + r) < n16);
                float p = valid ? __expf(val[tt][r] - M) : 0.f;
                val[tt][r] = p;           // unnormalized probs (local ref M)
                psum += p;
            }
        }
    }

    // ---- G = X diag(pool_w) X^T on the same tiles; dot with P in-register ----
    float dot = 0.f;
    #pragma unroll
    for (int tt = 0; tt < 3; ++tt) {
        if (tt < NT) {
            f16x8 yp = fa[tt] * pwf;
            f32x4 z = {0.f, 0.f, 0.f, 0.f};
            f32x4 g = __builtin_amdgcn_mfma_f32_16x16x32_f16(yp, fb[tt], z, 0, 0, 0);
            #pragma unroll
            for (int r = 0; r < 4; ++r)
                dot += val[tt][r] * g[r]; // masked entries have p=0
        }
    }

    // ---- reduce within wave, then exact cross-wave merge via LDS ----
    #pragma unroll
    for (int off = 32; off >= 1; off >>= 1) {
        dot  += __shfl_xor(dot, off);
        psum += __shfl_xor(psum, off);
    }
    if (lane == 0) {
        red[wave][0] = M;
        red[wave][1] = psum;
        red[wave][2] = dot;
    }
    __syncthreads();

    if (tid == 0) {
        float Mg = fmaxf(fmaxf(red[0][0], red[1][0]), fmaxf(red[2][0], red[3][0]));
        float den = 0.f, num = 0.f;
        #pragma unroll
        for (int w = 0; w < 4; ++w) {
            float s = __expf(red[w][0] - Mg);   // e^{-inf}=0 handles empty waves
            den += red[w][1] * s;
            num += red[w][2] * s;
        }
        out[batch] = num / den + pool_b[0];
    }
}

extern "C" void kernel_launch(void* const* d_in, const int* in_sizes, int n_in,
                              void* d_out, int out_size, void* d_ws, size_t ws_size,
                              hipStream_t stream) {
    const float* x      = (const float*)d_in[0];
    const float* attn_w = (const float*)d_in[1];
    const float* attn_b = (const float*)d_in[2];
    const float* attn_h = (const float*)d_in[3];
    const float* pool_w = (const float*)d_in[4];
    const float* pool_b = (const float*)d_in[5];
    float* out = (float*)d_out;
    int B = in_sizes[0] / (FDIM * EDIM);
    afm_kernel<<<B, 256, 0, stream>>>(x, attn_w, attn_b, attn_h, pool_w, pool_b, out);
}